// Round 1
// baseline (1419.702 us; speedup 1.0000x reference)
//
#include <hip/hip_runtime.h>

#define N_ROWS 32768
#define K_CODES 1024
#define D_DIM 256
#define NELEM 8388608

// ws layout
#define WS_COUNTS 0            // float[1024]
#define WS_DW 1024             // float[262144]
#define WS_ENORM 263168        // float[1024]
#define WS_ROWBEST_BYTES 1056768  // u64[32768]
#define WS_IDX_BYTES 1318912      // int[32768]

// out offsets (floats)
#define O_ZQ 0
#define O_LOSS 8388608
#define O_IDX 8388609
#define O_EMB 8421377
#define O_CS 8683521
#define O_EMAW 8684545

__device__ __forceinline__ unsigned int fenc(float f) {
    unsigned int u = __float_as_uint(f);
    return (u & 0x80000000u) ? ~u : (u | 0x80000000u);
}
__device__ __forceinline__ unsigned long long umin64(unsigned long long a, unsigned long long b) {
    return a < b ? a : b;
}

__global__ __launch_bounds__(256) void k_init(float* ws) {
    int i = blockIdx.x * 256 + threadIdx.x;
    if (i < 263168) ws[i] = 0.0f;
    unsigned long long* rb = (unsigned long long*)((char*)ws + WS_ROWBEST_BYTES);
    if (i < N_ROWS) rb[i] = 0xFFFFFFFFFFFFFFFFull;
}

__global__ __launch_bounds__(256) void k_enorm(const float* __restrict__ emb, float* __restrict__ enorm) {
    int k = blockIdx.x * 256 + threadIdx.x;
    if (k >= K_CODES) return;
    const float4* p = (const float4*)(emb + (size_t)k * D_DIM);
    float ax = 0.f, ay = 0.f, az = 0.f, aw = 0.f;
    #pragma unroll 8
    for (int i = 0; i < 64; i++) {
        float4 v = p[i];
        ax += v.x * v.x; ay += v.y * v.y; az += v.z * v.z; aw += v.w * v.w;
    }
    enorm[k] = (ax + ay) + (az + aw);
}

// distances + argmin: block = 64 rows x 64 codes, thread micro-tile 4x4
__global__ __launch_bounds__(256) void k_argmin(const float* __restrict__ z_e,
                                                const float* __restrict__ emb,
                                                const float* __restrict__ enorm,
                                                unsigned long long* __restrict__ row_best) {
    __shared__ float zs[64 * 64];                 // [k][row]
    __shared__ float es[64 * 64];                 // [k][code]
    __shared__ unsigned long long bestp[64 * 16]; // [row][tx]

    const int ct = blockIdx.x;   // code tile 0..15
    const int rt = blockIdx.y;   // row tile 0..511
    const int t = threadIdx.x;
    const int tx = t & 15, ty = t >> 4;
    const int n0 = rt * 64;
    const float* zb = z_e + (size_t)(n0 >> 10) * 262144 + (n0 & 1023); // + d*1024 + j
    const float* eb = emb + (size_t)ct * 64 * D_DIM;

    float4 en = *(const float4*)(enorm + ct * 64 + tx * 4);

    float dot[4][4];
    #pragma unroll
    for (int i = 0; i < 4; i++)
        #pragma unroll
        for (int j = 0; j < 4; j++) dot[i][j] = 0.0f;

    for (int kc = 0; kc < 4; kc++) {
        // stage z chunk: zs[k][j] = z[n0+j][kc*64+k]
        #pragma unroll
        for (int p = 0; p < 4; p++) {
            int idx = p * 256 + t;
            int kk = idx >> 4, j4 = idx & 15;
            *(float4*)(zs + kk * 64 + j4 * 4) =
                *(const float4*)(zb + (size_t)(kc * 64 + kk) * 1024 + j4 * 4);
        }
        // stage e chunk transposed: es[k][c] = emb[ct*64+c][kc*64+k]
        #pragma unroll
        for (int p = 0; p < 4; p++) {
            int idx = p * 256 + t;
            int k4 = idx >> 6, c = idx & 63;
            float4 v = *(const float4*)(eb + (size_t)c * 256 + kc * 64 + k4 * 4);
            es[(k4 * 4 + 0) * 64 + c] = v.x;
            es[(k4 * 4 + 1) * 64 + c] = v.y;
            es[(k4 * 4 + 2) * 64 + c] = v.z;
            es[(k4 * 4 + 3) * 64 + c] = v.w;
        }
        __syncthreads();
        #pragma unroll 8
        for (int k = 0; k < 64; k++) {
            float4 a = *(const float4*)(zs + k * 64 + ty * 4);
            float4 b4 = *(const float4*)(es + k * 64 + tx * 4);
            dot[0][0] += a.x * b4.x; dot[0][1] += a.x * b4.y; dot[0][2] += a.x * b4.z; dot[0][3] += a.x * b4.w;
            dot[1][0] += a.y * b4.x; dot[1][1] += a.y * b4.y; dot[1][2] += a.y * b4.z; dot[1][3] += a.y * b4.w;
            dot[2][0] += a.z * b4.x; dot[2][1] += a.z * b4.y; dot[2][2] += a.z * b4.z; dot[2][3] += a.z * b4.w;
            dot[3][0] += a.w * b4.x; dot[3][1] += a.w * b4.y; dot[3][2] += a.w * b4.z; dot[3][3] += a.w * b4.w;
        }
        __syncthreads();
    }

    float enj[4] = {en.x, en.y, en.z, en.w};
    #pragma unroll
    for (int i = 0; i < 4; i++) {
        int r = ty * 4 + i;
        unsigned long long best = 0xFFFFFFFFFFFFFFFFull;
        #pragma unroll
        for (int j = 0; j < 4; j++) {
            float dist = enj[j] - 2.0f * dot[i][j];
            unsigned long long pk = ((unsigned long long)fenc(dist) << 32) |
                                    (unsigned int)(ct * 64 + tx * 4 + j);
            best = umin64(best, pk);
        }
        bestp[r * 16 + tx] = best;
    }
    __syncthreads();
    if (t < 64) {
        unsigned long long m = bestp[t * 16];
        #pragma unroll
        for (int j = 1; j < 16; j++) m = umin64(m, bestp[t * 16 + j]);
        atomicMin(&row_best[n0 + t], m);
    }
}

__global__ __launch_bounds__(256) void k_fin_idx(const unsigned long long* __restrict__ rb,
                                                 int* __restrict__ idxs, float* __restrict__ out) {
    int i = blockIdx.x * 256 + threadIdx.x;
    if (i < N_ROWS) {
        int id = (int)(rb[i] & 0xFFFFFFFFull);
        idxs[i] = id;
        out[O_IDX + i] = (float)id;
    }
}

// counts + dw via atomics; block = one (b,h) pair (32 rows)
__global__ __launch_bounds__(256) void k_scatter(const float* __restrict__ z_e,
                                                 const int* __restrict__ idxs,
                                                 float* __restrict__ counts,
                                                 float* __restrict__ dw) {
    int blk = blockIdx.x;            // b*32 + h
    int t = threadIdx.x;
    int w = t & 31, half = t >> 5;   // half 0..7
    int b = blk >> 5, h = blk & 31;
    int n = blk * 32 + w;
    int id = idxs[n];
    if (t < 32) atomicAdd(&counts[idxs[blk * 32 + t]], 1.0f);
    const float* zb = z_e + (size_t)b * 262144 + h * 32 + w;
    float* dwr = dw + (size_t)id * 256;
    #pragma unroll 4
    for (int i = 0; i < 32; i++) {
        int d = half * 32 + i;
        atomicAdd(&dwr[d], zb[(size_t)d * 1024]);
    }
}

__global__ __launch_bounds__(256) void k_fin_code(const float* __restrict__ ema_cs,
                                                  const float* __restrict__ ema_w,
                                                  const float* __restrict__ counts,
                                                  const float* __restrict__ dw,
                                                  float* __restrict__ out) {
    int k = blockIdx.x, d = threadIdx.x;
    float cs = 0.99f * ema_cs[k] + 0.01f * counts[k];
    size_t kd = (size_t)k * 256 + d;
    float nw = 0.99f * ema_w[kd] + 0.01f * dw[kd];
    float ne = nw / (cs + 1e-5f);
    out[O_EMB + kd] = ne;
    out[O_EMAW + kd] = nw;
    if (d == 0) out[O_CS + k] = cs;
    if (k == 0 && d == 0) out[O_LOSS] = 0.0f;
}

__global__ __launch_bounds__(256) void k_gather(const float* __restrict__ z_e,
                                                const int* __restrict__ idxs,
                                                float* __restrict__ out) {
    int g = blockIdx.x * 256 + threadIdx.x;   // 0..2097151
    int e0 = g * 4;
    int hw = e0 & 1023, d = (e0 >> 10) & 255, b = e0 >> 18;
    int n = b * 1024 + hw;
    int4 id4 = *(const int4*)(idxs + n);
    const float* ne = out + O_EMB;
    float q0 = ne[(size_t)id4.x * 256 + d];
    float q1 = ne[(size_t)id4.y * 256 + d];
    float q2 = ne[(size_t)id4.z * 256 + d];
    float q3 = ne[(size_t)id4.w * 256 + d];
    float4 z4 = *(const float4*)(z_e + e0);
    float4 o;
    o.x = z4.x + (q0 - z4.x);
    o.y = z4.y + (q1 - z4.y);
    o.z = z4.z + (q2 - z4.z);
    o.w = z4.w + (q3 - z4.w);
    *(float4*)(out + O_ZQ + e0) = o;
    float dx = z4.x - q0, dy = z4.y - q1, dz = z4.z - q2, dww = z4.w - q3;
    float acc = dx * dx + dy * dy + dz * dz + dww * dww;
    // wave + block reduce
    #pragma unroll
    for (int off = 32; off >= 1; off >>= 1) acc += __shfl_down(acc, off, 64);
    __shared__ float red[4];
    int lane = threadIdx.x & 63, wv = threadIdx.x >> 6;
    if (lane == 0) red[wv] = acc;
    __syncthreads();
    if (threadIdx.x == 0) {
        float s = (red[0] + red[1]) + (red[2] + red[3]);
        atomicAdd(out + O_LOSS, s * 2.9802322387695312e-08f); // * BETA / NELEM
    }
}

extern "C" void kernel_launch(void* const* d_in, const int* in_sizes, int n_in,
                              void* d_out, int out_size, void* d_ws, size_t ws_size,
                              hipStream_t stream) {
    const float* z_e = (const float*)d_in[0];
    const float* emb = (const float*)d_in[1];
    const float* ema_cs = (const float*)d_in[2];
    const float* ema_w = (const float*)d_in[3];
    float* out = (float*)d_out;
    float* ws = (float*)d_ws;

    float* counts = ws + WS_COUNTS;
    float* dw = ws + WS_DW;
    float* enorm = ws + WS_ENORM;
    unsigned long long* row_best = (unsigned long long*)((char*)d_ws + WS_ROWBEST_BYTES);
    int* idxs = (int*)((char*)d_ws + WS_IDX_BYTES);

    k_init<<<1028, 256, 0, stream>>>(ws);
    k_enorm<<<4, 256, 0, stream>>>(emb, enorm);
    k_argmin<<<dim3(16, 512), 256, 0, stream>>>(z_e, emb, enorm, row_best);
    k_fin_idx<<<128, 256, 0, stream>>>(row_best, idxs, out);
    k_scatter<<<1024, 256, 0, stream>>>(z_e, idxs, counts, dw);
    k_fin_code<<<1024, 256, 0, stream>>>(ema_cs, ema_w, counts, dw, out);
    k_gather<<<8192, 256, 0, stream>>>(z_e, idxs, out);
}

// Round 2
// 538.016 us; speedup vs baseline: 2.6388x; 2.6388x over previous
//
#include <hip/hip_runtime.h>

#define N_ROWS 32768
#define K_CODES 1024
#define D_DIM 256
#define NELEM 8388608

// ws layout
#define WS_COUNTS 0            // float[1024]
#define WS_DW 1024             // float[262144]
#define WS_ENORM 263168        // float[1024]
#define WS_ROWBEST_BYTES 1056768  // u64[32768]
#define WS_IDX_BYTES 1318912      // int[32768]

// out offsets (floats)
#define O_ZQ 0
#define O_LOSS 8388608
#define O_IDX 8388609
#define O_EMB 8421377
#define O_CS 8683521
#define O_EMAW 8684545

__device__ __forceinline__ unsigned int fenc(float f) {
    unsigned int u = __float_as_uint(f);
    return (u & 0x80000000u) ? ~u : (u | 0x80000000u);
}
__device__ __forceinline__ unsigned long long umin64(unsigned long long a, unsigned long long b) {
    return a < b ? a : b;
}

__global__ __launch_bounds__(256) void k_init(float* ws) {
    int i = blockIdx.x * 256 + threadIdx.x;
    if (i < 263168) ws[i] = 0.0f;
    unsigned long long* rb = (unsigned long long*)((char*)ws + WS_ROWBEST_BYTES);
    if (i < N_ROWS) rb[i] = 0xFFFFFFFFFFFFFFFFull;
}

__global__ __launch_bounds__(256) void k_enorm(const float* __restrict__ emb, float* __restrict__ enorm) {
    int k = blockIdx.x * 256 + threadIdx.x;
    if (k >= K_CODES) return;
    const float4* p = (const float4*)(emb + (size_t)k * D_DIM);
    float ax = 0.f, ay = 0.f, az = 0.f, aw = 0.f;
    #pragma unroll 8
    for (int i = 0; i < 64; i++) {
        float4 v = p[i];
        ax += v.x * v.x; ay += v.y * v.y; az += v.z * v.z; aw += v.w * v.w;
    }
    enorm[k] = (ax + ay) + (az + aw);
}

// distances + argmin: block = 64 rows x 64 codes, thread micro-tile 4x4
__global__ __launch_bounds__(256) void k_argmin(const float* __restrict__ z_e,
                                                const float* __restrict__ emb,
                                                const float* __restrict__ enorm,
                                                unsigned long long* __restrict__ row_best) {
    __shared__ float zs[64 * 64];                 // [k][row]
    __shared__ float es[64 * 64];                 // [k][code]
    __shared__ unsigned long long bestp[64 * 16]; // [row][tx]

    const int ct = blockIdx.x;   // code tile 0..15
    const int rt = blockIdx.y;   // row tile 0..511
    const int t = threadIdx.x;
    const int tx = t & 15, ty = t >> 4;
    const int n0 = rt * 64;
    const float* zb = z_e + (size_t)(n0 >> 10) * 262144 + (n0 & 1023); // + d*1024 + j
    const float* eb = emb + (size_t)ct * 64 * D_DIM;

    float4 en = *(const float4*)(enorm + ct * 64 + tx * 4);

    float dot[4][4];
    #pragma unroll
    for (int i = 0; i < 4; i++)
        #pragma unroll
        for (int j = 0; j < 4; j++) dot[i][j] = 0.0f;

    for (int kc = 0; kc < 4; kc++) {
        // stage z chunk: zs[k][j] = z[n0+j][kc*64+k]
        #pragma unroll
        for (int p = 0; p < 4; p++) {
            int idx = p * 256 + t;
            int kk = idx >> 4, j4 = idx & 15;
            *(float4*)(zs + kk * 64 + j4 * 4) =
                *(const float4*)(zb + (size_t)(kc * 64 + kk) * 1024 + j4 * 4);
        }
        // stage e chunk transposed: es[k][c] = emb[ct*64+c][kc*64+k]
        #pragma unroll
        for (int p = 0; p < 4; p++) {
            int idx = p * 256 + t;
            int k4 = idx >> 6, c = idx & 63;
            float4 v = *(const float4*)(eb + (size_t)c * 256 + kc * 64 + k4 * 4);
            es[(k4 * 4 + 0) * 64 + c] = v.x;
            es[(k4 * 4 + 1) * 64 + c] = v.y;
            es[(k4 * 4 + 2) * 64 + c] = v.z;
            es[(k4 * 4 + 3) * 64 + c] = v.w;
        }
        __syncthreads();
        #pragma unroll 8
        for (int k = 0; k < 64; k++) {
            float4 a = *(const float4*)(zs + k * 64 + ty * 4);
            float4 b4 = *(const float4*)(es + k * 64 + tx * 4);
            dot[0][0] += a.x * b4.x; dot[0][1] += a.x * b4.y; dot[0][2] += a.x * b4.z; dot[0][3] += a.x * b4.w;
            dot[1][0] += a.y * b4.x; dot[1][1] += a.y * b4.y; dot[1][2] += a.y * b4.z; dot[1][3] += a.y * b4.w;
            dot[2][0] += a.z * b4.x; dot[2][1] += a.z * b4.y; dot[2][2] += a.z * b4.z; dot[2][3] += a.z * b4.w;
            dot[3][0] += a.w * b4.x; dot[3][1] += a.w * b4.y; dot[3][2] += a.w * b4.z; dot[3][3] += a.w * b4.w;
        }
        __syncthreads();
    }

    float enj[4] = {en.x, en.y, en.z, en.w};
    #pragma unroll
    for (int i = 0; i < 4; i++) {
        int r = ty * 4 + i;
        unsigned long long best = 0xFFFFFFFFFFFFFFFFull;
        #pragma unroll
        for (int j = 0; j < 4; j++) {
            float dist = enj[j] - 2.0f * dot[i][j];
            unsigned long long pk = ((unsigned long long)fenc(dist) << 32) |
                                    (unsigned int)(ct * 64 + tx * 4 + j);
            best = umin64(best, pk);
        }
        bestp[r * 16 + tx] = best;
    }
    __syncthreads();
    if (t < 64) {
        unsigned long long m = bestp[t * 16];
        #pragma unroll
        for (int j = 1; j < 16; j++) m = umin64(m, bestp[t * 16 + j]);
        atomicMin(&row_best[n0 + t], m);
    }
}

__global__ __launch_bounds__(256) void k_fin_idx(const unsigned long long* __restrict__ rb,
                                                 int* __restrict__ idxs, float* __restrict__ out) {
    int i = blockIdx.x * 256 + threadIdx.x;
    if (i < N_ROWS) {
        int id = (int)(rb[i] & 0xFFFFFFFFull);
        idxs[i] = id;
        out[O_IDX + i] = (float)id;
    }
}

// histogram of indices: 8 blocks x 4096 ids, LDS pre-aggregation
__global__ __launch_bounds__(256) void k_counts(const int* __restrict__ idxs,
                                                float* __restrict__ counts) {
    __shared__ float hist[K_CODES];
    int t = threadIdx.x;
    #pragma unroll
    for (int j = 0; j < 4; j++) hist[j * 256 + t] = 0.0f;
    __syncthreads();
    int n0 = blockIdx.x * 4096;
    #pragma unroll
    for (int i = 0; i < 16; i++) {
        int id = idxs[n0 + i * 256 + t];
        atomicAdd(&hist[id], 1.0f);
    }
    __syncthreads();
    #pragma unroll
    for (int j = 0; j < 4; j++) {
        float h = hist[j * 256 + t];
        if (h != 0.0f) atomicAdd(&counts[j * 256 + t], h);
    }
}

// dw segment-sum: block = (n-chunk s, dim d). LDS acc[1024] over codes,
// coalesced z reads (contiguous hw), then <=1024 global atomics per block
// spread over distinct addresses (max 8 per address -> no hot-line serialization).
__global__ __launch_bounds__(256) void k_dw(const float* __restrict__ z_e,
                                            const int* __restrict__ idxs,
                                            float* __restrict__ dw) {
    __shared__ float acc[K_CODES];
    int t = threadIdx.x;
    int s = blockIdx.x;   // 0..7 n-chunk
    int d = blockIdx.y;   // 0..255
    #pragma unroll
    for (int j = 0; j < 4; j++) acc[j * 256 + t] = 0.0f;
    __syncthreads();
    int n0 = s * 4096;
    #pragma unroll
    for (int i = 0; i < 16; i++) {
        int n = n0 + i * 256 + t;
        int id = idxs[n];
        int b = n >> 10, hw = n & 1023;
        float v = z_e[(size_t)b * 262144 + (size_t)d * 1024 + hw];
        atomicAdd(&acc[id], v);
    }
    __syncthreads();
    #pragma unroll
    for (int j = 0; j < 4; j++) {
        int k = j * 256 + t;
        float a = acc[k];
        if (a != 0.0f) atomicAdd(&dw[(size_t)k * 256 + d], a);
    }
}

__global__ __launch_bounds__(256) void k_fin_code(const float* __restrict__ ema_cs,
                                                  const float* __restrict__ ema_w,
                                                  const float* __restrict__ counts,
                                                  const float* __restrict__ dw,
                                                  float* __restrict__ out) {
    int k = blockIdx.x, d = threadIdx.x;
    float cs = 0.99f * ema_cs[k] + 0.01f * counts[k];
    size_t kd = (size_t)k * 256 + d;
    float nw = 0.99f * ema_w[kd] + 0.01f * dw[kd];
    float ne = nw / (cs + 1e-5f);
    out[O_EMB + kd] = ne;
    out[O_EMAW + kd] = nw;
    if (d == 0) out[O_CS + k] = cs;
    if (k == 0 && d == 0) out[O_LOSS] = 0.0f;
}

__global__ __launch_bounds__(256) void k_gather(const float* __restrict__ z_e,
                                                const int* __restrict__ idxs,
                                                float* __restrict__ out) {
    int g = blockIdx.x * 256 + threadIdx.x;   // 0..2097151
    int e0 = g * 4;
    int hw = e0 & 1023, d = (e0 >> 10) & 255, b = e0 >> 18;
    int n = b * 1024 + hw;
    int4 id4 = *(const int4*)(idxs + n);
    const float* ne = out + O_EMB;
    float q0 = ne[(size_t)id4.x * 256 + d];
    float q1 = ne[(size_t)id4.y * 256 + d];
    float q2 = ne[(size_t)id4.z * 256 + d];
    float q3 = ne[(size_t)id4.w * 256 + d];
    float4 z4 = *(const float4*)(z_e + e0);
    float4 o;
    o.x = z4.x + (q0 - z4.x);
    o.y = z4.y + (q1 - z4.y);
    o.z = z4.z + (q2 - z4.z);
    o.w = z4.w + (q3 - z4.w);
    *(float4*)(out + O_ZQ + e0) = o;
    float dx = z4.x - q0, dy = z4.y - q1, dz = z4.z - q2, dww = z4.w - q3;
    float acc = dx * dx + dy * dy + dz * dz + dww * dww;
    // wave + block reduce
    #pragma unroll
    for (int off = 32; off >= 1; off >>= 1) acc += __shfl_down(acc, off, 64);
    __shared__ float red[4];
    int lane = threadIdx.x & 63, wv = threadIdx.x >> 6;
    if (lane == 0) red[wv] = acc;
    __syncthreads();
    if (threadIdx.x == 0) {
        float s = (red[0] + red[1]) + (red[2] + red[3]);
        atomicAdd(out + O_LOSS, s * 2.9802322387695312e-08f); // * BETA / NELEM
    }
}

extern "C" void kernel_launch(void* const* d_in, const int* in_sizes, int n_in,
                              void* d_out, int out_size, void* d_ws, size_t ws_size,
                              hipStream_t stream) {
    const float* z_e = (const float*)d_in[0];
    const float* emb = (const float*)d_in[1];
    const float* ema_cs = (const float*)d_in[2];
    const float* ema_w = (const float*)d_in[3];
    float* out = (float*)d_out;
    float* ws = (float*)d_ws;

    float* counts = ws + WS_COUNTS;
    float* dw = ws + WS_DW;
    float* enorm = ws + WS_ENORM;
    unsigned long long* row_best = (unsigned long long*)((char*)d_ws + WS_ROWBEST_BYTES);
    int* idxs = (int*)((char*)d_ws + WS_IDX_BYTES);

    k_init<<<1028, 256, 0, stream>>>(ws);
    k_enorm<<<4, 256, 0, stream>>>(emb, enorm);
    k_argmin<<<dim3(16, 512), 256, 0, stream>>>(z_e, emb, enorm, row_best);
    k_fin_idx<<<128, 256, 0, stream>>>(row_best, idxs, out);
    k_counts<<<8, 256, 0, stream>>>(idxs, counts);
    k_dw<<<dim3(8, 256), 256, 0, stream>>>(z_e, idxs, dw);
    k_fin_code<<<1024, 256, 0, stream>>>(ema_cs, ema_w, counts, dw, out);
    k_gather<<<8192, 256, 0, stream>>>(z_e, idxs, out);
}

// Round 3
// 404.486 us; speedup vs baseline: 3.5099x; 1.3301x over previous
//
#include <hip/hip_runtime.h>
#include <stdint.h>

#define N_ROWS 32768
#define K_CODES 1024
#define D_DIM 256
#define NELEM 8388608

// ws layout (proven <=1.45MB in prior rounds)
#define WS_COUNTS 0               // float[1024]
#define WS_DW 1024                // float[262144]
#define WS_ENORM 263168           // float[1024]
#define WS_ROWBEST_BYTES 1056768  // u64[32768]
#define WS_IDX_BYTES 1318912      // int[32768]

// out offsets (floats)
#define O_ZQ 0
#define O_LOSS 8388608
#define O_IDX 8388609
#define O_EMB 8421377
#define O_CS 8683521
#define O_EMAW 8684545

// scratch carved out of d_out (written before the real outputs land there):
//   Zp: fp16[32768][512]  = bytes [0, 33554432)        == z_q_st region (exact fit)
//   Ep: fp16[1024][768]   = bytes [33685520, 35258384) == new_embedding/ema_w region (16B aligned)
#define EP_BYTE_OFF 33685520

typedef _Float16 half8 __attribute__((ext_vector_type(8)));
typedef float f32x4 __attribute__((ext_vector_type(4)));

__device__ __forceinline__ unsigned int fenc(float f) {
    unsigned int u = __float_as_uint(f);
    return (u & 0x80000000u) ? ~u : (u | 0x80000000u);
}
__device__ __forceinline__ unsigned long long umin64(unsigned long long a, unsigned long long b) {
    return a < b ? a : b;
}
__device__ __forceinline__ void gll16(const void* g, void* l) {
    __builtin_amdgcn_global_load_lds((const __attribute__((address_space(1))) void*)g,
                                     (__attribute__((address_space(3))) void*)l, 16, 0, 0);
}

__global__ __launch_bounds__(256) void k_init(float* ws) {
    int i = blockIdx.x * 256 + threadIdx.x;
    if (i < 263168) ws[i] = 0.0f;
    unsigned long long* rb = (unsigned long long*)((char*)ws + WS_ROWBEST_BYTES);
    if (i < N_ROWS) rb[i] = 0xFFFFFFFFFFFFFFFFull;
}

// emb (1024x256 f32) -> Ep [eh | eh | el] fp16, + enorm
__global__ __launch_bounds__(256) void k_conv_e(const float* __restrict__ emb,
                                                _Float16* __restrict__ Ep,
                                                float* __restrict__ enorm) {
    int k = blockIdx.x, d = threadIdx.x;
    float v = emb[k * 256 + d];
    _Float16 h = (_Float16)v;
    _Float16 l = (_Float16)(v - (float)h);
    _Float16* row = Ep + (size_t)k * 768;
    row[d] = h; row[256 + d] = h; row[512 + d] = l;
    float s = v * v;
    #pragma unroll
    for (int off = 32; off >= 1; off >>= 1) s += __shfl_down(s, off, 64);
    __shared__ float red[4];
    if ((d & 63) == 0) red[d >> 6] = s;
    __syncthreads();
    if (d == 0) enorm[k] = (red[0] + red[1]) + (red[2] + red[3]);
}

// z_e[b][d][hw] f32 -> Zp[n][0..255]=hi, [n][256..511]=lo (fp16, d-contiguous)
__global__ __launch_bounds__(256) void k_conv_z(const float* __restrict__ z_e,
                                                _Float16* __restrict__ Zp) {
    __shared__ float lt[64 * 68];
    int t = threadIdx.x;
    int hw0 = blockIdx.x * 64, d0 = blockIdx.y * 64, b = blockIdx.z;
    const float* src = z_e + (size_t)b * 262144 + (size_t)d0 * 1024 + hw0;
    int dl = t >> 4, hl = (t & 15) * 4;
    #pragma unroll
    for (int i = 0; i < 4; i++) {
        int d = dl + i * 16;
        float4 v = *(const float4*)(src + (size_t)d * 1024 + hl);
        lt[(hl + 0) * 68 + d] = v.x;
        lt[(hl + 1) * 68 + d] = v.y;
        lt[(hl + 2) * 68 + d] = v.z;
        lt[(hl + 3) * 68 + d] = v.w;
    }
    __syncthreads();
    int hr = t >> 2, seg = t & 3;
    int n = b * 1024 + hw0 + hr;
    half8 hi[2], lo[2];
    #pragma unroll
    for (int p = 0; p < 2; p++) {
        #pragma unroll
        for (int j = 0; j < 8; j++) {
            float v = lt[hr * 68 + seg * 16 + p * 8 + j];
            _Float16 h = (_Float16)v;
            hi[p][j] = h;
            lo[p][j] = (_Float16)(v - (float)h);
        }
    }
    _Float16* dst = Zp + (size_t)n * 512 + d0 + seg * 16;
    *(half8*)(dst) = hi[0];
    *(half8*)(dst + 8) = hi[1];
    *(half8*)(dst + 256) = lo[0];
    *(half8*)(dst + 264) = lo[1];
}

// fused fp16-split GEMM (K'=768) + argmin epilogue.
// block tile 128 rows x 128 codes, 4 waves of 64x64, mfma 16x16x32 f16.
__global__ __launch_bounds__(256) void k_mm(const _Float16* __restrict__ Zp,
                                            const _Float16* __restrict__ Ep,
                                            const float* __restrict__ enorm,
                                            unsigned long long* __restrict__ row_best) {
    __shared__ _Float16 Za[128 * 32];   // [row][32 halfs]
    __shared__ _Float16 Ea[128 * 32];   // [code][32 halfs]
    __shared__ unsigned long long bestp[128];

    int t = threadIdx.x;
    int lane = t & 63, wv = t >> 6;
    int ct = blockIdx.x, rt = blockIdx.y;
    int row0 = rt * 128, code0 = ct * 128;

    if (t < 128) bestp[t] = 0xFFFFFFFFFFFFFFFFull;

    int wr = wv >> 1, wc = wv & 1;
    int lane15 = lane & 15, q = lane >> 4;

    f32x4 acc[4][4];
    #pragma unroll
    for (int r = 0; r < 4; r++)
        #pragma unroll
        for (int cc = 0; cc < 4; cc++)
            acc[r][cc] = (f32x4){0.f, 0.f, 0.f, 0.f};

    // staging: wave wv covers rows [wv*32, wv*32+32) of each tile; lane l ->
    // row +(l>>2), 16B segment (l&3). LDS dest is wave-uniform base + lane*16.
    int srow = wv * 32 + (lane >> 2);
    int sseg = lane & 3;
    const char* zg0 = (const char*)(Zp + (size_t)(row0 + srow) * 512) + sseg * 16;
    const char* zg1 = zg0 + 16 * 512 * 2;
    const char* eg0 = (const char*)(Ep + (size_t)(code0 + srow) * 768) + sseg * 16;
    const char* eg1 = eg0 + 16 * 768 * 2;
    _Float16* zl0 = Za + wv * 1024;
    _Float16* el0 = Ea + wv * 1024;

    for (int c = 0; c < 24; c++) {
        int kz = (c < 16) ? c : (c - 16);   // Zp K-chunk ([zh|zl] reused for the zh*el term)
        gll16(zg0 + kz * 64, zl0);
        gll16(zg1 + kz * 64, zl0 + 512);
        gll16(eg0 + c * 64, el0);
        gll16(eg1 + c * 64, el0 + 512);
        __syncthreads();
        half8 a[4], b[4];
        #pragma unroll
        for (int r = 0; r < 4; r++)
            a[r] = *(const half8*)(Za + (wr * 64 + r * 16 + lane15) * 32 + q * 8);
        #pragma unroll
        for (int cc = 0; cc < 4; cc++)
            b[cc] = *(const half8*)(Ea + (wc * 64 + cc * 16 + lane15) * 32 + q * 8);
        #pragma unroll
        for (int r = 0; r < 4; r++)
            #pragma unroll
            for (int cc = 0; cc < 4; cc++)
                acc[r][cc] = __builtin_amdgcn_mfma_f32_16x16x32_f16(a[r], b[cc], acc[r][cc], 0, 0, 0);
        __syncthreads();
    }

    // epilogue: dist = ||e||^2 - 2*dot; C/D layout col=lane&15, row=q*4+reg
    float en_c[4];
    #pragma unroll
    for (int cc = 0; cc < 4; cc++) en_c[cc] = enorm[code0 + wc * 64 + cc * 16 + lane15];
    #pragma unroll
    for (int r = 0; r < 4; r++) {
        #pragma unroll
        for (int j = 0; j < 4; j++) {
            int rl = wr * 64 + r * 16 + q * 4 + j;
            unsigned long long best = 0xFFFFFFFFFFFFFFFFull;
            #pragma unroll
            for (int cc = 0; cc < 4; cc++) {
                float dist = en_c[cc] - 2.0f * acc[r][cc][j];
                unsigned long long pk = ((unsigned long long)fenc(dist) << 32) |
                                        (unsigned int)(code0 + wc * 64 + cc * 16 + lane15);
                best = umin64(best, pk);
            }
            atomicMin(&bestp[rl], best);
        }
    }
    __syncthreads();
    if (t < 128) atomicMin(&row_best[row0 + t], bestp[t]);
}

__global__ __launch_bounds__(256) void k_fin_idx(const unsigned long long* __restrict__ rb,
                                                 int* __restrict__ idxs, float* __restrict__ out) {
    int i = blockIdx.x * 256 + threadIdx.x;
    if (i < N_ROWS) {
        int id = (int)(rb[i] & 0xFFFFFFFFull);
        idxs[i] = id;
        out[O_IDX + i] = (float)id;
    }
}

__global__ __launch_bounds__(256) void k_counts(const int* __restrict__ idxs,
                                                float* __restrict__ counts) {
    __shared__ float hist[K_CODES];
    int t = threadIdx.x;
    #pragma unroll
    for (int j = 0; j < 4; j++) hist[j * 256 + t] = 0.0f;
    __syncthreads();
    int n0 = blockIdx.x * 1024;
    #pragma unroll
    for (int i = 0; i < 4; i++) {
        int id = idxs[n0 + i * 256 + t];
        atomicAdd(&hist[id], 1.0f);
    }
    __syncthreads();
    #pragma unroll
    for (int j = 0; j < 4; j++) {
        float h = hist[j * 256 + t];
        if (h != 0.0f) atomicAdd(&counts[j * 256 + t], h);
    }
}

__global__ __launch_bounds__(256) void k_dw(const float* __restrict__ z_e,
                                            const int* __restrict__ idxs,
                                            float* __restrict__ dw) {
    __shared__ float acc[K_CODES];
    int t = threadIdx.x;
    int s = blockIdx.x;   // 0..7 n-chunk
    int d = blockIdx.y;   // 0..255
    #pragma unroll
    for (int j = 0; j < 4; j++) acc[j * 256 + t] = 0.0f;
    __syncthreads();
    int n0 = s * 4096;
    #pragma unroll
    for (int i = 0; i < 16; i++) {
        int n = n0 + i * 256 + t;
        int id = idxs[n];
        int b = n >> 10, hw = n & 1023;
        float v = z_e[(size_t)b * 262144 + (size_t)d * 1024 + hw];
        atomicAdd(&acc[id], v);
    }
    __syncthreads();
    #pragma unroll
    for (int j = 0; j < 4; j++) {
        int k = j * 256 + t;
        float a = acc[k];
        if (a != 0.0f) atomicAdd(&dw[(size_t)k * 256 + d], a);
    }
}

__global__ __launch_bounds__(256) void k_fin_code(const float* __restrict__ ema_cs,
                                                  const float* __restrict__ ema_w,
                                                  const float* __restrict__ counts,
                                                  const float* __restrict__ dw,
                                                  float* __restrict__ out) {
    int k = blockIdx.x, d = threadIdx.x;
    float cs = 0.99f * ema_cs[k] + 0.01f * counts[k];
    size_t kd = (size_t)k * 256 + d;
    float nw = 0.99f * ema_w[kd] + 0.01f * dw[kd];
    float ne = nw / (cs + 1e-5f);
    out[O_EMB + kd] = ne;
    out[O_EMAW + kd] = nw;
    if (d == 0) out[O_CS + k] = cs;
    if (k == 0 && d == 0) out[O_LOSS] = 0.0f;
}

__global__ __launch_bounds__(256) void k_gather(const float* __restrict__ z_e,
                                                const int* __restrict__ idxs,
                                                float* __restrict__ out) {
    int g = blockIdx.x * 256 + threadIdx.x;
    int e0 = g * 4;
    int hw = e0 & 1023, d = (e0 >> 10) & 255, b = e0 >> 18;
    int n = b * 1024 + hw;
    int4 id4 = *(const int4*)(idxs + n);
    const float* ne = out + O_EMB;
    float q0 = ne[(size_t)id4.x * 256 + d];
    float q1 = ne[(size_t)id4.y * 256 + d];
    float q2 = ne[(size_t)id4.z * 256 + d];
    float q3 = ne[(size_t)id4.w * 256 + d];
    float4 z4 = *(const float4*)(z_e + e0);
    float4 o;
    o.x = z4.x + (q0 - z4.x);
    o.y = z4.y + (q1 - z4.y);
    o.z = z4.z + (q2 - z4.z);
    o.w = z4.w + (q3 - z4.w);
    *(float4*)(out + O_ZQ + e0) = o;
    float dx = z4.x - q0, dy = z4.y - q1, dz = z4.z - q2, dww = z4.w - q3;
    float accl = dx * dx + dy * dy + dz * dz + dww * dww;
    #pragma unroll
    for (int off = 32; off >= 1; off >>= 1) accl += __shfl_down(accl, off, 64);
    __shared__ float red[4];
    int lane = threadIdx.x & 63, wv = threadIdx.x >> 6;
    if (lane == 0) red[wv] = accl;
    __syncthreads();
    if (threadIdx.x == 0) {
        float s = (red[0] + red[1]) + (red[2] + red[3]);
        atomicAdd(out + O_LOSS, s * 2.9802322387695312e-08f); // * BETA / NELEM
    }
}

extern "C" void kernel_launch(void* const* d_in, const int* in_sizes, int n_in,
                              void* d_out, int out_size, void* d_ws, size_t ws_size,
                              hipStream_t stream) {
    const float* z_e = (const float*)d_in[0];
    const float* emb = (const float*)d_in[1];
    const float* ema_cs = (const float*)d_in[2];
    const float* ema_w = (const float*)d_in[3];
    float* out = (float*)d_out;
    float* ws = (float*)d_ws;

    float* counts = ws + WS_COUNTS;
    float* dw = ws + WS_DW;
    float* enorm = ws + WS_ENORM;
    unsigned long long* row_best = (unsigned long long*)((char*)d_ws + WS_ROWBEST_BYTES);
    int* idxs = (int*)((char*)d_ws + WS_IDX_BYTES);

    _Float16* Zp = (_Float16*)d_out;                       // overwritten by k_gather at the end
    _Float16* Ep = (_Float16*)((char*)d_out + EP_BYTE_OFF); // overwritten by k_fin_code

    k_init<<<1028, 256, 0, stream>>>(ws);
    k_conv_e<<<1024, 256, 0, stream>>>(emb, Ep, enorm);
    k_conv_z<<<dim3(16, 4, 32), 256, 0, stream>>>(z_e, Zp);
    k_mm<<<dim3(8, 256), 256, 0, stream>>>(Zp, Ep, enorm, row_best);
    k_fin_idx<<<128, 256, 0, stream>>>(row_best, idxs, out);
    k_counts<<<32, 256, 0, stream>>>(idxs, counts);
    k_dw<<<dim3(8, 256), 256, 0, stream>>>(z_e, idxs, dw);
    k_fin_code<<<1024, 256, 0, stream>>>(ema_cs, ema_w, counts, dw, out);
    k_gather<<<8192, 256, 0, stream>>>(z_e, idxs, out);
}

// Round 4
// 364.804 us; speedup vs baseline: 3.8917x; 1.1088x over previous
//
#include <hip/hip_runtime.h>
#include <stdint.h>

#define N_ROWS 32768
#define K_CODES 1024
#define D_DIM 256
#define NELEM 8388608

// ws layout (proven <=1.45MB in prior rounds)
#define WS_COUNTS 0               // float[1024]
#define WS_DW 1024                // float[262144]
#define WS_ENORM 263168           // float[1024]
#define WS_ROWBEST_BYTES 1056768  // u64[32768]
#define WS_IDX_BYTES 1318912      // int[32768]

// out offsets (floats)
#define O_ZQ 0
#define O_LOSS 8388608
#define O_IDX 8388609
#define O_EMB 8421377
#define O_CS 8683521
#define O_EMAW 8684545

// scratch carved out of d_out:
//   Zp: seg-major fp16 [64 segs][32768 rows][16B] = bytes [0, 33554432)  (z_q_st region, exact fit)
//   Ep: seg-major fp16 [64 segs][1024 rows][16B]  = 1 MB at EP_BYTE_OFF  (new_embedding region, written later)
//   segs 0..31 = hi halves (d = seg*8..), segs 32..63 = lo halves
#define EP_BYTE_OFF 33685520

typedef _Float16 half8 __attribute__((ext_vector_type(8)));
typedef float f32x16 __attribute__((ext_vector_type(16)));

__device__ __forceinline__ unsigned int fenc(float f) {
    unsigned int u = __float_as_uint(f);
    return (u & 0x80000000u) ? ~u : (u | 0x80000000u);
}
__device__ __forceinline__ unsigned long long umin64(unsigned long long a, unsigned long long b) {
    return a < b ? a : b;
}
__device__ __forceinline__ void gll16(const void* g, void* l) {
    __builtin_amdgcn_global_load_lds((const __attribute__((address_space(1))) void*)g,
                                     (__attribute__((address_space(3))) void*)l, 16, 0, 0);
}

__global__ __launch_bounds__(256) void k_init(float* ws) {
    int i = blockIdx.x * 256 + threadIdx.x;
    if (i < 263168) ws[i] = 0.0f;
    unsigned long long* rb = (unsigned long long*)((char*)ws + WS_ROWBEST_BYTES);
    if (i < N_ROWS) rb[i] = 0xFFFFFFFFFFFFFFFFull;
}

// emb (1024x256 f32) -> Ep seg-major [64 segs][1024][8 halfs], + enorm
__global__ __launch_bounds__(256) void k_conv_e(const float* __restrict__ emb,
                                                _Float16* __restrict__ Ep,
                                                float* __restrict__ enorm) {
    int k = blockIdx.x, d = threadIdx.x;
    float v = emb[k * 256 + d];
    _Float16 h = (_Float16)v;
    _Float16 l = (_Float16)(v - (float)h);
    int s = d >> 3, sub = d & 7;
    Ep[((size_t)s * 1024 + k) * 8 + sub] = h;
    Ep[((size_t)(32 + s) * 1024 + k) * 8 + sub] = l;
    float sq = v * v;
    #pragma unroll
    for (int off = 32; off >= 1; off >>= 1) sq += __shfl_down(sq, off, 64);
    __shared__ float red[4];
    if ((d & 63) == 0) red[d >> 6] = sq;
    __syncthreads();
    if (d == 0) enorm[k] = (red[0] + red[1]) + (red[2] + red[3]);
}

// z_e[b][d][hw] f32 -> Zp seg-major [64 segs][32768 rows][8 halfs]
__global__ __launch_bounds__(256) void k_conv_z(const float* __restrict__ z_e,
                                                _Float16* __restrict__ Zp) {
    __shared__ float lt[64 * 68];
    int t = threadIdx.x;
    int hw0 = blockIdx.x * 64, d0 = blockIdx.y * 64, b = blockIdx.z;
    const float* src = z_e + (size_t)b * 262144 + (size_t)d0 * 1024 + hw0;
    int dl = t >> 4, hl = (t & 15) * 4;
    #pragma unroll
    for (int i = 0; i < 4; i++) {
        int d = dl + i * 16;
        float4 v = *(const float4*)(src + (size_t)d * 1024 + hl);
        lt[(hl + 0) * 68 + d] = v.x;
        lt[(hl + 1) * 68 + d] = v.y;
        lt[(hl + 2) * 68 + d] = v.z;
        lt[(hl + 3) * 68 + d] = v.w;
    }
    __syncthreads();
    int hr = t >> 2, seg = t & 3;
    int n = b * 1024 + hw0 + hr;
    int sg0 = (d0 >> 3) + seg * 2;   // global hi-seg of first 8 halfs
    half8 hi[2], lo[2];
    #pragma unroll
    for (int p = 0; p < 2; p++) {
        #pragma unroll
        for (int j = 0; j < 8; j++) {
            float v = lt[hr * 68 + seg * 16 + p * 8 + j];
            _Float16 h = (_Float16)v;
            hi[p][j] = h;
            lo[p][j] = (_Float16)(v - (float)h);
        }
    }
    *(half8*)(Zp + ((size_t)(sg0 + 0) * 32768 + n) * 8) = hi[0];
    *(half8*)(Zp + ((size_t)(sg0 + 1) * 32768 + n) * 8) = hi[1];
    *(half8*)(Zp + ((size_t)(32 + sg0) * 32768 + n) * 8) = lo[0];
    *(half8*)(Zp + ((size_t)(33 + sg0) * 32768 + n) * 8) = lo[1];
}

// fused fp16-split GEMM (3 terms: zh.eh + zl.eh + zh.el) + argmin epilogue.
// block tile 128x128, 4 waves 64x64, mfma 32x32x16 f16, K=64/iter, 12 iters.
__global__ __launch_bounds__(256) void k_mm(const _Float16* __restrict__ Zp,
                                            const _Float16* __restrict__ Ep,
                                            const float* __restrict__ enorm,
                                            unsigned long long* __restrict__ row_best) {
    __shared__ __align__(16) char smem[32768];
    _Float16* Za = (_Float16*)smem;            // [8 segs][128 rows][8 halfs] 16KB
    _Float16* Ea = (_Float16*)(smem + 16384);  // same, for codes
    unsigned long long* slot = (unsigned long long*)smem; // [128][32] after loop

    int t = threadIdx.x;
    int lane = t & 63, wv = t >> 6;
    int b = blockIdx.x;
    int rt = (b & 7) + ((b >> 6) << 3);   // same-Z blocks -> same XCD (assumes %8 round-robin)
    int ct = (b >> 3) & 7;
    int row0 = rt * 128, code0 = ct * 128;

    int wr = wv >> 1, wc = wv & 1;
    int m31 = lane & 31, ko = lane >> 5;

    f32x16 acc[2][2];
    #pragma unroll
    for (int i = 0; i < 2; i++)
        #pragma unroll
        for (int j = 0; j < 2; j++)
            #pragma unroll
            for (int r = 0; r < 16; r++) acc[i][j][r] = 0.0f;

    // staging: wave wv stages segs {2wv, 2wv+1}; lane l -> row l (+64 for 2nd call)
    const char* zgl = (const char*)Zp + ((size_t)(2 * wv) * 32768 + row0 + lane) * 16;
    const char* egl = (const char*)Ep + ((size_t)(2 * wv) * 1024 + code0 + lane) * 16;
    _Float16* zld = Za + (2 * wv) * 1024;
    _Float16* eld = Ea + (2 * wv) * 1024;

    for (int c = 0; c < 12; c++) {
        int kz = (c < 8) ? c : (c - 8);                                  // Z 64-half group
        int ge = (c < 4) ? c * 8 : (c < 8) ? (c - 4) * 8 : 32 + (c - 8) * 8; // E seg base
        const char* zg = zgl + (size_t)kz * 8 * 32768 * 16;
        const char* eg = egl + (size_t)ge * 1024 * 16;
        gll16(zg, zld);
        gll16(zg + 64 * 16, zld + 512);
        gll16(zg + 32768 * 16, zld + 1024);
        gll16(zg + 32768 * 16 + 64 * 16, zld + 1536);
        gll16(eg, eld);
        gll16(eg + 64 * 16, eld + 512);
        gll16(eg + 1024 * 16, eld + 1024);
        gll16(eg + 1024 * 16 + 64 * 16, eld + 1536);
        __syncthreads();
        #pragma unroll
        for (int ks = 0; ks < 4; ks++) {
            int sseg = 2 * ks + ko;
            half8 a0 = *(const half8*)(Za + sseg * 1024 + (wr * 64 + m31) * 8);
            half8 a1 = *(const half8*)(Za + sseg * 1024 + (wr * 64 + 32 + m31) * 8);
            half8 b0 = *(const half8*)(Ea + sseg * 1024 + (wc * 64 + m31) * 8);
            half8 b1 = *(const half8*)(Ea + sseg * 1024 + (wc * 64 + 32 + m31) * 8);
            acc[0][0] = __builtin_amdgcn_mfma_f32_32x32x16_f16(a0, b0, acc[0][0], 0, 0, 0);
            acc[0][1] = __builtin_amdgcn_mfma_f32_32x32x16_f16(a0, b1, acc[0][1], 0, 0, 0);
            acc[1][0] = __builtin_amdgcn_mfma_f32_32x32x16_f16(a1, b0, acc[1][0], 0, 0, 0);
            acc[1][1] = __builtin_amdgcn_mfma_f32_32x32x16_f16(a1, b1, acc[1][1], 0, 0, 0);
        }
        __syncthreads();
    }

    // epilogue: dist = ||e||^2 - 2*dot
    // C/D 32x32 layout: col=lane&31, row=(reg&3)+8*(reg>>2)+4*(lane>>5)
    float en0 = enorm[code0 + wc * 64 + m31];
    float en1 = enorm[code0 + wc * 64 + 32 + m31];
    unsigned int col0 = code0 + wc * 64 + m31;
    unsigned int col1 = col0 + 32;

    // slot[row][ (m31+row)&31 ]: wc=0 waves plain-write, wc=1 waves 2-way atomicMin
    if (wc == 0) {
        #pragma unroll
        for (int mt = 0; mt < 2; mt++)
            #pragma unroll
            for (int j = 0; j < 16; j++) {
                int row = wr * 64 + mt * 32 + 4 * ko + (j & 3) + 8 * (j >> 2);
                unsigned long long p0 = ((unsigned long long)fenc(en0 - 2.0f * acc[mt][0][j]) << 32) | col0;
                unsigned long long p1 = ((unsigned long long)fenc(en1 - 2.0f * acc[mt][1][j]) << 32) | col1;
                slot[row * 32 + ((m31 + row) & 31)] = umin64(p0, p1);
            }
    }
    __syncthreads();
    if (wc == 1) {
        #pragma unroll
        for (int mt = 0; mt < 2; mt++)
            #pragma unroll
            for (int j = 0; j < 16; j++) {
                int row = wr * 64 + mt * 32 + 4 * ko + (j & 3) + 8 * (j >> 2);
                unsigned long long p0 = ((unsigned long long)fenc(en0 - 2.0f * acc[mt][0][j]) << 32) | col0;
                unsigned long long p1 = ((unsigned long long)fenc(en1 - 2.0f * acc[mt][1][j]) << 32) | col1;
                atomicMin(&slot[row * 32 + ((m31 + row) & 31)], umin64(p0, p1));
            }
    }
    __syncthreads();
    if (t < 128) {
        unsigned long long m = slot[t * 32 + (t & 31)];
        #pragma unroll
        for (int i = 1; i < 32; i++) m = umin64(m, slot[t * 32 + ((i + t) & 31)]);
        atomicMin(&row_best[row0 + t], m);
    }
}

__global__ __launch_bounds__(256) void k_fin_idx(const unsigned long long* __restrict__ rb,
                                                 int* __restrict__ idxs, float* __restrict__ out) {
    int i = blockIdx.x * 256 + threadIdx.x;
    if (i < N_ROWS) {
        int id = (int)(rb[i] & 0xFFFFFFFFull);
        idxs[i] = id;
        out[O_IDX + i] = (float)id;
    }
}

__global__ __launch_bounds__(256) void k_counts(const int* __restrict__ idxs,
                                                float* __restrict__ counts) {
    __shared__ float hist[K_CODES];
    int t = threadIdx.x;
    #pragma unroll
    for (int j = 0; j < 4; j++) hist[j * 256 + t] = 0.0f;
    __syncthreads();
    int n0 = blockIdx.x * 1024;
    #pragma unroll
    for (int i = 0; i < 4; i++) {
        int id = idxs[n0 + i * 256 + t];
        atomicAdd(&hist[id], 1.0f);
    }
    __syncthreads();
    #pragma unroll
    for (int j = 0; j < 4; j++) {
        float h = hist[j * 256 + t];
        if (h != 0.0f) atomicAdd(&counts[j * 256 + t], h);
    }
}

__global__ __launch_bounds__(256) void k_dw(const float* __restrict__ z_e,
                                            const int* __restrict__ idxs,
                                            float* __restrict__ dw) {
    __shared__ float acc[K_CODES];
    int t = threadIdx.x;
    int s = blockIdx.x;   // 0..7 n-chunk
    int d = blockIdx.y;   // 0..255
    #pragma unroll
    for (int j = 0; j < 4; j++) acc[j * 256 + t] = 0.0f;
    __syncthreads();
    int n0 = s * 4096;
    #pragma unroll
    for (int i = 0; i < 16; i++) {
        int n = n0 + i * 256 + t;
        int id = idxs[n];
        int b = n >> 10, hw = n & 1023;
        float v = z_e[(size_t)b * 262144 + (size_t)d * 1024 + hw];
        atomicAdd(&acc[id], v);
    }
    __syncthreads();
    #pragma unroll
    for (int j = 0; j < 4; j++) {
        int k = j * 256 + t;
        float a = acc[k];
        if (a != 0.0f) atomicAdd(&dw[(size_t)k * 256 + d], a);
    }
}

__global__ __launch_bounds__(256) void k_fin_code(const float* __restrict__ ema_cs,
                                                  const float* __restrict__ ema_w,
                                                  const float* __restrict__ counts,
                                                  const float* __restrict__ dw,
                                                  float* __restrict__ out) {
    int k = blockIdx.x, d = threadIdx.x;
    float cs = 0.99f * ema_cs[k] + 0.01f * counts[k];
    size_t kd = (size_t)k * 256 + d;
    float nw = 0.99f * ema_w[kd] + 0.01f * dw[kd];
    float ne = nw / (cs + 1e-5f);
    out[O_EMB + kd] = ne;
    out[O_EMAW + kd] = nw;
    if (d == 0) out[O_CS + k] = cs;
    if (k == 0 && d == 0) out[O_LOSS] = 0.0f;
}

__global__ __launch_bounds__(256) void k_gather(const float* __restrict__ z_e,
                                                const int* __restrict__ idxs,
                                                float* __restrict__ out) {
    int g = blockIdx.x * 256 + threadIdx.x;
    int e0 = g * 4;
    int hw = e0 & 1023, d = (e0 >> 10) & 255, b = e0 >> 18;
    int n = b * 1024 + hw;
    int4 id4 = *(const int4*)(idxs + n);
    const float* ne = out + O_EMB;
    float q0 = ne[(size_t)id4.x * 256 + d];
    float q1 = ne[(size_t)id4.y * 256 + d];
    float q2 = ne[(size_t)id4.z * 256 + d];
    float q3 = ne[(size_t)id4.w * 256 + d];
    float4 z4 = *(const float4*)(z_e + e0);
    float4 o;
    o.x = z4.x + (q0 - z4.x);
    o.y = z4.y + (q1 - z4.y);
    o.z = z4.z + (q2 - z4.z);
    o.w = z4.w + (q3 - z4.w);
    *(float4*)(out + O_ZQ + e0) = o;
    float dx = z4.x - q0, dy = z4.y - q1, dz = z4.z - q2, dww = z4.w - q3;
    float accl = dx * dx + dy * dy + dz * dz + dww * dww;
    #pragma unroll
    for (int off = 32; off >= 1; off >>= 1) accl += __shfl_down(accl, off, 64);
    __shared__ float red[4];
    int lane = threadIdx.x & 63, wv = threadIdx.x >> 6;
    if (lane == 0) red[wv] = accl;
    __syncthreads();
    if (threadIdx.x == 0) {
        float s = (red[0] + red[1]) + (red[2] + red[3]);
        atomicAdd(out + O_LOSS, s * 2.9802322387695312e-08f); // * BETA / NELEM
    }
}

extern "C" void kernel_launch(void* const* d_in, const int* in_sizes, int n_in,
                              void* d_out, int out_size, void* d_ws, size_t ws_size,
                              hipStream_t stream) {
    const float* z_e = (const float*)d_in[0];
    const float* emb = (const float*)d_in[1];
    const float* ema_cs = (const float*)d_in[2];
    const float* ema_w = (const float*)d_in[3];
    float* out = (float*)d_out;
    float* ws = (float*)d_ws;

    float* counts = ws + WS_COUNTS;
    float* dw = ws + WS_DW;
    float* enorm = ws + WS_ENORM;
    unsigned long long* row_best = (unsigned long long*)((char*)d_ws + WS_ROWBEST_BYTES);
    int* idxs = (int*)((char*)d_ws + WS_IDX_BYTES);

    _Float16* Zp = (_Float16*)d_out;                        // overwritten by k_gather at the end
    _Float16* Ep = (_Float16*)((char*)d_out + EP_BYTE_OFF); // overwritten by k_fin_code

    k_init<<<1028, 256, 0, stream>>>(ws);
    k_conv_e<<<1024, 256, 0, stream>>>(emb, Ep, enorm);
    k_conv_z<<<dim3(16, 4, 32), 256, 0, stream>>>(z_e, Zp);
    k_mm<<<2048, 256, 0, stream>>>(Zp, Ep, enorm, row_best);
    k_fin_idx<<<128, 256, 0, stream>>>(row_best, idxs, out);
    k_counts<<<32, 256, 0, stream>>>(idxs, counts);
    k_dw<<<dim3(8, 256), 256, 0, stream>>>(z_e, idxs, dw);
    k_fin_code<<<1024, 256, 0, stream>>>(ema_cs, ema_w, counts, dw, out);
    k_gather<<<8192, 256, 0, stream>>>(z_e, idxs, out);
}

// Round 5
// 296.029 us; speedup vs baseline: 4.7958x; 1.2323x over previous
//
#include <hip/hip_runtime.h>
#include <stdint.h>

#define N_ROWS 32768
#define K_CODES 1024
#define D_DIM 256
#define NELEM 8388608

// ws layout (proven <=1.45MB in prior rounds)
#define WS_COUNTS 0               // float[1024]
#define WS_DW 1024                // float[262144]
#define WS_ENORM 263168           // float[1024]
#define WS_ROWBEST_BYTES 1056768  // u64[32768]
#define WS_IDX_BYTES 1318912      // int[32768]

// out offsets (floats)
#define O_ZQ 0
#define O_LOSS 8388608
#define O_IDX 8388609
#define O_EMB 8421377
#define O_CS 8683521
#define O_EMAW 8684545

// scratch carved out of d_out:
//   Zp: seg-major fp16 [64 segs][32768 rows][16B] = bytes [0, 33554432)  (z_q_st region, exact fit)
//   Ep: seg-major fp16 [64 segs][1024 rows][16B]  = 1 MB at EP_BYTE_OFF  (new_embedding region, written later)
//   segs 0..31 = hi halves (d = seg*8..), segs 32..63 = lo halves
#define EP_BYTE_OFF 33685520

typedef _Float16 half8 __attribute__((ext_vector_type(8)));
typedef float f32x16 __attribute__((ext_vector_type(16)));

__device__ __forceinline__ unsigned int fenc(float f) {
    unsigned int u = __float_as_uint(f);
    return (u & 0x80000000u) ? ~u : (u | 0x80000000u);
}
__device__ __forceinline__ unsigned long long umin64(unsigned long long a, unsigned long long b) {
    return a < b ? a : b;
}
__device__ __forceinline__ void gll16(const void* g, void* l) {
    __builtin_amdgcn_global_load_lds((const __attribute__((address_space(1))) void*)g,
                                     (__attribute__((address_space(3))) void*)l, 16, 0, 0);
}

__global__ __launch_bounds__(256) void k_init(float* ws) {
    int i = blockIdx.x * 256 + threadIdx.x;
    if (i < 263168) ws[i] = 0.0f;
    unsigned long long* rb = (unsigned long long*)((char*)ws + WS_ROWBEST_BYTES);
    if (i < N_ROWS) rb[i] = 0xFFFFFFFFFFFFFFFFull;
}

// emb (1024x256 f32) -> Ep seg-major [64 segs][1024][8 halfs], + enorm
__global__ __launch_bounds__(256) void k_conv_e(const float* __restrict__ emb,
                                                _Float16* __restrict__ Ep,
                                                float* __restrict__ enorm) {
    int k = blockIdx.x, d = threadIdx.x;
    float v = emb[k * 256 + d];
    _Float16 h = (_Float16)v;
    _Float16 l = (_Float16)(v - (float)h);
    int s = d >> 3, sub = d & 7;
    Ep[((size_t)s * 1024 + k) * 8 + sub] = h;
    Ep[((size_t)(32 + s) * 1024 + k) * 8 + sub] = l;
    float sq = v * v;
    #pragma unroll
    for (int off = 32; off >= 1; off >>= 1) sq += __shfl_down(sq, off, 64);
    __shared__ float red[4];
    if ((d & 63) == 0) red[d >> 6] = sq;
    __syncthreads();
    if (d == 0) enorm[k] = (red[0] + red[1]) + (red[2] + red[3]);
}

// z_e[b][d][hw] f32 -> Zp seg-major [64 segs][32768 rows][8 halfs]
__global__ __launch_bounds__(256) void k_conv_z(const float* __restrict__ z_e,
                                                _Float16* __restrict__ Zp) {
    __shared__ float lt[64 * 68];
    int t = threadIdx.x;
    int hw0 = blockIdx.x * 64, d0 = blockIdx.y * 64, b = blockIdx.z;
    const float* src = z_e + (size_t)b * 262144 + (size_t)d0 * 1024 + hw0;
    int dl = t >> 4, hl = (t & 15) * 4;
    #pragma unroll
    for (int i = 0; i < 4; i++) {
        int d = dl + i * 16;
        float4 v = *(const float4*)(src + (size_t)d * 1024 + hl);
        lt[(hl + 0) * 68 + d] = v.x;
        lt[(hl + 1) * 68 + d] = v.y;
        lt[(hl + 2) * 68 + d] = v.z;
        lt[(hl + 3) * 68 + d] = v.w;
    }
    __syncthreads();
    int hr = t >> 2, seg = t & 3;
    int n = b * 1024 + hw0 + hr;
    int sg0 = (d0 >> 3) + seg * 2;   // global hi-seg of first 8 halfs
    half8 hi[2], lo[2];
    #pragma unroll
    for (int p = 0; p < 2; p++) {
        #pragma unroll
        for (int j = 0; j < 8; j++) {
            float v = lt[hr * 68 + seg * 16 + p * 8 + j];
            _Float16 h = (_Float16)v;
            hi[p][j] = h;
            lo[p][j] = (_Float16)(v - (float)h);
        }
    }
    *(half8*)(Zp + ((size_t)(sg0 + 0) * 32768 + n) * 8) = hi[0];
    *(half8*)(Zp + ((size_t)(sg0 + 1) * 32768 + n) * 8) = hi[1];
    *(half8*)(Zp + ((size_t)(32 + sg0) * 32768 + n) * 8) = lo[0];
    *(half8*)(Zp + ((size_t)(33 + sg0) * 32768 + n) * 8) = lo[1];
}

// fused fp16-split GEMM (3 terms: zh.eh + zl.eh + zh.el) + argmin epilogue.
// block tile 128x128, 4 waves 64x64, mfma 32x32x16 f16, K=64/iter, 12 iters.
__global__ __launch_bounds__(256) void k_mm(const _Float16* __restrict__ Zp,
                                            const _Float16* __restrict__ Ep,
                                            const float* __restrict__ enorm,
                                            unsigned long long* __restrict__ row_best) {
    __shared__ __align__(16) char smem[32768];
    _Float16* Za = (_Float16*)smem;            // [8 segs][128 rows][8 halfs] 16KB
    _Float16* Ea = (_Float16*)(smem + 16384);  // same, for codes
    unsigned long long* slot = (unsigned long long*)smem; // [128][32] after loop

    int t = threadIdx.x;
    int lane = t & 63, wv = t >> 6;
    int b = blockIdx.x;
    int rt = (b & 7) + ((b >> 6) << 3);   // same-Z blocks -> same XCD (assumes %8 round-robin)
    int ct = (b >> 3) & 7;
    int row0 = rt * 128, code0 = ct * 128;

    int wr = wv >> 1, wc = wv & 1;
    int m31 = lane & 31, ko = lane >> 5;

    f32x16 acc[2][2];
    #pragma unroll
    for (int i = 0; i < 2; i++)
        #pragma unroll
        for (int j = 0; j < 2; j++)
            #pragma unroll
            for (int r = 0; r < 16; r++) acc[i][j][r] = 0.0f;

    // staging: wave wv stages segs {2wv, 2wv+1}; lane l -> row l (+64 for 2nd call)
    const char* zgl = (const char*)Zp + ((size_t)(2 * wv) * 32768 + row0 + lane) * 16;
    const char* egl = (const char*)Ep + ((size_t)(2 * wv) * 1024 + code0 + lane) * 16;
    _Float16* zld = Za + (2 * wv) * 1024;
    _Float16* eld = Ea + (2 * wv) * 1024;

    for (int c = 0; c < 12; c++) {
        int kz = (c < 8) ? c : (c - 8);                                  // Z 64-half group
        int ge = (c < 4) ? c * 8 : (c < 8) ? (c - 4) * 8 : 32 + (c - 8) * 8; // E seg base
        const char* zg = zgl + (size_t)kz * 8 * 32768 * 16;
        const char* eg = egl + (size_t)ge * 1024 * 16;
        gll16(zg, zld);
        gll16(zg + 64 * 16, zld + 512);
        gll16(zg + 32768 * 16, zld + 1024);
        gll16(zg + 32768 * 16 + 64 * 16, zld + 1536);
        gll16(eg, eld);
        gll16(eg + 64 * 16, eld + 512);
        gll16(eg + 1024 * 16, eld + 1024);
        gll16(eg + 1024 * 16 + 64 * 16, eld + 1536);
        __syncthreads();
        #pragma unroll
        for (int ks = 0; ks < 4; ks++) {
            int sseg = 2 * ks + ko;
            half8 a0 = *(const half8*)(Za + sseg * 1024 + (wr * 64 + m31) * 8);
            half8 a1 = *(const half8*)(Za + sseg * 1024 + (wr * 64 + 32 + m31) * 8);
            half8 b0 = *(const half8*)(Ea + sseg * 1024 + (wc * 64 + m31) * 8);
            half8 b1 = *(const half8*)(Ea + sseg * 1024 + (wc * 64 + 32 + m31) * 8);
            acc[0][0] = __builtin_amdgcn_mfma_f32_32x32x16_f16(a0, b0, acc[0][0], 0, 0, 0);
            acc[0][1] = __builtin_amdgcn_mfma_f32_32x32x16_f16(a0, b1, acc[0][1], 0, 0, 0);
            acc[1][0] = __builtin_amdgcn_mfma_f32_32x32x16_f16(a1, b0, acc[1][0], 0, 0, 0);
            acc[1][1] = __builtin_amdgcn_mfma_f32_32x32x16_f16(a1, b1, acc[1][1], 0, 0, 0);
        }
        __syncthreads();
    }

    // epilogue: dist = ||e||^2 - 2*dot
    // C/D 32x32 layout: col=lane&31, row=(reg&3)+8*(reg>>2)+4*(lane>>5)
    float en0 = enorm[code0 + wc * 64 + m31];
    float en1 = enorm[code0 + wc * 64 + 32 + m31];
    unsigned int col0 = code0 + wc * 64 + m31;
    unsigned int col1 = col0 + 32;

    // slot[row][ (m31+row)&31 ]: wc=0 waves plain-write, wc=1 waves 2-way atomicMin
    if (wc == 0) {
        #pragma unroll
        for (int mt = 0; mt < 2; mt++)
            #pragma unroll
            for (int j = 0; j < 16; j++) {
                int row = wr * 64 + mt * 32 + 4 * ko + (j & 3) + 8 * (j >> 2);
                unsigned long long p0 = ((unsigned long long)fenc(en0 - 2.0f * acc[mt][0][j]) << 32) | col0;
                unsigned long long p1 = ((unsigned long long)fenc(en1 - 2.0f * acc[mt][1][j]) << 32) | col1;
                slot[row * 32 + ((m31 + row) & 31)] = umin64(p0, p1);
            }
    }
    __syncthreads();
    if (wc == 1) {
        #pragma unroll
        for (int mt = 0; mt < 2; mt++)
            #pragma unroll
            for (int j = 0; j < 16; j++) {
                int row = wr * 64 + mt * 32 + 4 * ko + (j & 3) + 8 * (j >> 2);
                unsigned long long p0 = ((unsigned long long)fenc(en0 - 2.0f * acc[mt][0][j]) << 32) | col0;
                unsigned long long p1 = ((unsigned long long)fenc(en1 - 2.0f * acc[mt][1][j]) << 32) | col1;
                atomicMin(&slot[row * 32 + ((m31 + row) & 31)], umin64(p0, p1));
            }
    }
    __syncthreads();
    if (t < 128) {
        unsigned long long m = slot[t * 32 + (t & 31)];
        #pragma unroll
        for (int i = 1; i < 32; i++) m = umin64(m, slot[t * 32 + ((i + t) & 31)]);
        atomicMin(&row_best[row0 + t], m);
    }
}

__global__ __launch_bounds__(256) void k_fin_idx(const unsigned long long* __restrict__ rb,
                                                 int* __restrict__ idxs, float* __restrict__ out) {
    int i = blockIdx.x * 256 + threadIdx.x;
    if (i < N_ROWS) {
        int id = (int)(rb[i] & 0xFFFFFFFFull);
        idxs[i] = id;
        out[O_IDX + i] = (float)id;
    }
}

__global__ __launch_bounds__(256) void k_counts(const int* __restrict__ idxs,
                                                float* __restrict__ counts) {
    __shared__ float hist[K_CODES];
    int t = threadIdx.x;
    #pragma unroll
    for (int j = 0; j < 4; j++) hist[j * 256 + t] = 0.0f;
    __syncthreads();
    int n0 = blockIdx.x * 1024;
    #pragma unroll
    for (int i = 0; i < 4; i++) {
        int id = idxs[n0 + i * 256 + t];
        atomicAdd(&hist[id], 1.0f);
    }
    __syncthreads();
    #pragma unroll
    for (int j = 0; j < 4; j++) {
        float h = hist[j * 256 + t];
        if (h != 0.0f) atomicAdd(&counts[j * 256 + t], h);
    }
}

__global__ __launch_bounds__(256) void k_dw(const float* __restrict__ z_e,
                                            const int* __restrict__ idxs,
                                            float* __restrict__ dw) {
    __shared__ float acc[K_CODES];
    int t = threadIdx.x;
    int s = blockIdx.x;   // 0..7 n-chunk
    int d = blockIdx.y;   // 0..255
    #pragma unroll
    for (int j = 0; j < 4; j++) acc[j * 256 + t] = 0.0f;
    __syncthreads();
    int n0 = s * 4096;
    #pragma unroll
    for (int i = 0; i < 16; i++) {
        int n = n0 + i * 256 + t;
        int id = idxs[n];
        int b = n >> 10, hw = n & 1023;
        float v = z_e[(size_t)b * 262144 + (size_t)d * 1024 + hw];
        atomicAdd(&acc[id], v);
    }
    __syncthreads();
    #pragma unroll
    for (int j = 0; j < 4; j++) {
        int k = j * 256 + t;
        float a = acc[k];
        if (a != 0.0f) atomicAdd(&dw[(size_t)k * 256 + d], a);
    }
}

__global__ __launch_bounds__(256) void k_fin_code(const float* __restrict__ ema_cs,
                                                  const float* __restrict__ ema_w,
                                                  const float* __restrict__ counts,
                                                  const float* __restrict__ dw,
                                                  float* __restrict__ out) {
    int k = blockIdx.x, d = threadIdx.x;
    float cs = 0.99f * ema_cs[k] + 0.01f * counts[k];
    size_t kd = (size_t)k * 256 + d;
    float nw = 0.99f * ema_w[kd] + 0.01f * dw[kd];
    float ne = nw / (cs + 1e-5f);
    out[O_EMB + kd] = ne;
    out[O_EMAW + kd] = nw;
    if (d == 0) out[O_CS + k] = cs;
    if (k == 0 && d == 0) out[O_LOSS] = 0.0f;
}

// tiled transpose-gather: block = 64 hw x 64 d. z-tile staged in LDS,
// code rows gathered as coalesced float4 (4 lanes x 16B = one 64B line/row),
// straight-through output written back coalesced over hw.
__global__ __launch_bounds__(256) void k_gather(const float* __restrict__ z_e,
                                                const int* __restrict__ idxs,
                                                float* __restrict__ out) {
    __shared__ float lt[64 * 68];
    __shared__ int sid[64];
    __shared__ float red[4];
    int t = threadIdx.x;
    int hw0 = blockIdx.x * 64, d0 = blockIdx.y * 64, b = blockIdx.z;
    if (t < 64) sid[t] = idxs[b * 1024 + hw0 + t];
    const float* src = z_e + (size_t)b * 262144 + (size_t)d0 * 1024 + hw0;
    int dl = t >> 4, hl = (t & 15) * 4;
    #pragma unroll
    for (int i = 0; i < 4; i++) {
        int d = dl + i * 16;
        float4 v = *(const float4*)(src + (size_t)d * 1024 + hl);
        lt[(hl + 0) * 68 + d] = v.x;
        lt[(hl + 1) * 68 + d] = v.y;
        lt[(hl + 2) * 68 + d] = v.z;
        lt[(hl + 3) * 68 + d] = v.w;
    }
    __syncthreads();
    // gather + straight-through + loss, in place in lt
    int r = t >> 2, c = t & 3;
    const float* nrow = out + O_EMB + (size_t)sid[r] * 256 + d0;
    float lacc = 0.0f;
    #pragma unroll
    for (int it = 0; it < 4; it++) {
        int dd = it * 16 + c * 4;
        float4 q = *(const float4*)(nrow + dd);
        float* p = lt + r * 68 + dd;
        float z0 = p[0], z1 = p[1], z2 = p[2], z3 = p[3];
        p[0] = z0 + (q.x - z0);
        p[1] = z1 + (q.y - z1);
        p[2] = z2 + (q.z - z2);
        p[3] = z3 + (q.w - z3);
        float dx = z0 - q.x, dy = z1 - q.y, dz = z2 - q.z, dw4 = z3 - q.w;
        lacc += dx * dx + dy * dy + dz * dz + dw4 * dw4;
    }
    __syncthreads();
    float* dst = out + O_ZQ + (size_t)b * 262144 + (size_t)d0 * 1024 + hw0;
    #pragma unroll
    for (int i = 0; i < 4; i++) {
        int d = dl + i * 16;
        float4 w;
        w.x = lt[(hl + 0) * 68 + d];
        w.y = lt[(hl + 1) * 68 + d];
        w.z = lt[(hl + 2) * 68 + d];
        w.w = lt[(hl + 3) * 68 + d];
        *(float4*)(dst + (size_t)d * 1024 + hl) = w;
    }
    #pragma unroll
    for (int off = 32; off >= 1; off >>= 1) lacc += __shfl_down(lacc, off, 64);
    int lane = t & 63, wv = t >> 6;
    if (lane == 0) red[wv] = lacc;
    __syncthreads();
    if (t == 0) {
        float s = (red[0] + red[1]) + (red[2] + red[3]);
        atomicAdd(out + O_LOSS, s * 2.9802322387695312e-08f); // * BETA / NELEM
    }
}

extern "C" void kernel_launch(void* const* d_in, const int* in_sizes, int n_in,
                              void* d_out, int out_size, void* d_ws, size_t ws_size,
                              hipStream_t stream) {
    const float* z_e = (const float*)d_in[0];
    const float* emb = (const float*)d_in[1];
    const float* ema_cs = (const float*)d_in[2];
    const float* ema_w = (const float*)d_in[3];
    float* out = (float*)d_out;
    float* ws = (float*)d_ws;

    float* counts = ws + WS_COUNTS;
    float* dw = ws + WS_DW;
    float* enorm = ws + WS_ENORM;
    unsigned long long* row_best = (unsigned long long*)((char*)d_ws + WS_ROWBEST_BYTES);
    int* idxs = (int*)((char*)d_ws + WS_IDX_BYTES);

    _Float16* Zp = (_Float16*)d_out;                        // overwritten by k_gather at the end
    _Float16* Ep = (_Float16*)((char*)d_out + EP_BYTE_OFF); // overwritten by k_fin_code

    k_init<<<1028, 256, 0, stream>>>(ws);
    k_conv_e<<<1024, 256, 0, stream>>>(emb, Ep, enorm);
    k_conv_z<<<dim3(16, 4, 32), 256, 0, stream>>>(z_e, Zp);
    k_mm<<<2048, 256, 0, stream>>>(Zp, Ep, enorm, row_best);
    k_fin_idx<<<128, 256, 0, stream>>>(row_best, idxs, out);
    k_counts<<<32, 256, 0, stream>>>(idxs, counts);
    k_dw<<<dim3(8, 256), 256, 0, stream>>>(z_e, idxs, dw);
    k_fin_code<<<1024, 256, 0, stream>>>(ema_cs, ema_w, counts, dw, out);
    k_gather<<<dim3(16, 4, 32), 256, 0, stream>>>(z_e, idxs, out);
}

// Round 6
// 255.048 us; speedup vs baseline: 5.5664x; 1.1607x over previous
//
#include <hip/hip_runtime.h>
#include <stdint.h>

#define N_ROWS 32768
#define K_CODES 1024
#define D_DIM 256
#define NELEM 8388608

// ws layout (proven <=1.45MB in prior rounds)
#define WS_COUNTS 0               // float[1024]
#define WS_ENORM 263168           // float[1024]
#define WS_ROWBEST_BYTES 1056768  // u64[32768]
#define WS_IDX_BYTES 1318912      // int[32768]

// out offsets (floats)
#define O_ZQ 0
#define O_LOSS 8388608
#define O_IDX 8388609
#define O_EMB 8421377
#define O_CS 8683521
#define O_EMAW 8684545

// scratch carved out of d_out:
//   Zp: seg-major fp16 [64 segs][32768 rows][16B] = bytes [0, 33554432)  (z_q_st region)
//   Ep: seg-major fp16 [64 segs][1024 rows][16B]  = 1 MB at EP_BYTE_OFF  (new_embedding region)
//   part: float [8][256][1024] = 8 MB, reuses bytes [0, 8388608) of the Zp region AFTER k_mm
#define EP_BYTE_OFF 33685520

typedef _Float16 half8 __attribute__((ext_vector_type(8)));
typedef float f32x16 __attribute__((ext_vector_type(16)));

__device__ __forceinline__ unsigned int fenc(float f) {
    unsigned int u = __float_as_uint(f);
    return (u & 0x80000000u) ? ~u : (u | 0x80000000u);
}
__device__ __forceinline__ unsigned long long umin64(unsigned long long a, unsigned long long b) {
    return a < b ? a : b;
}
__device__ __forceinline__ void gll16(const void* g, void* l) {
    __builtin_amdgcn_global_load_lds((const __attribute__((address_space(1))) void*)g,
                                     (__attribute__((address_space(3))) void*)l, 16, 0, 0);
}

__global__ __launch_bounds__(256) void k_init(float* ws) {
    int i = blockIdx.x * 256 + threadIdx.x;
    if (i < 1024) ws[i] = 0.0f;   // counts
    unsigned long long* rb = (unsigned long long*)((char*)ws + WS_ROWBEST_BYTES);
    if (i < N_ROWS) rb[i] = 0xFFFFFFFFFFFFFFFFull;
}

// emb (1024x256 f32) -> Ep seg-major [64 segs][1024][8 halfs], + enorm
__global__ __launch_bounds__(256) void k_conv_e(const float* __restrict__ emb,
                                                _Float16* __restrict__ Ep,
                                                float* __restrict__ enorm) {
    int k = blockIdx.x, d = threadIdx.x;
    float v = emb[k * 256 + d];
    _Float16 h = (_Float16)v;
    _Float16 l = (_Float16)(v - (float)h);
    int s = d >> 3, sub = d & 7;
    Ep[((size_t)s * 1024 + k) * 8 + sub] = h;
    Ep[((size_t)(32 + s) * 1024 + k) * 8 + sub] = l;
    float sq = v * v;
    #pragma unroll
    for (int off = 32; off >= 1; off >>= 1) sq += __shfl_down(sq, off, 64);
    __shared__ float red[4];
    if ((d & 63) == 0) red[d >> 6] = sq;
    __syncthreads();
    if (d == 0) enorm[k] = (red[0] + red[1]) + (red[2] + red[3]);
}

// z_e[b][d][hw] f32 -> Zp seg-major [64 segs][32768 rows][8 halfs]
__global__ __launch_bounds__(256) void k_conv_z(const float* __restrict__ z_e,
                                                _Float16* __restrict__ Zp) {
    __shared__ float lt[64 * 68];
    int t = threadIdx.x;
    int hw0 = blockIdx.x * 64, d0 = blockIdx.y * 64, b = blockIdx.z;
    const float* src = z_e + (size_t)b * 262144 + (size_t)d0 * 1024 + hw0;
    int dl = t >> 4, hl = (t & 15) * 4;
    #pragma unroll
    for (int i = 0; i < 4; i++) {
        int d = dl + i * 16;
        float4 v = *(const float4*)(src + (size_t)d * 1024 + hl);
        lt[(hl + 0) * 68 + d] = v.x;
        lt[(hl + 1) * 68 + d] = v.y;
        lt[(hl + 2) * 68 + d] = v.z;
        lt[(hl + 3) * 68 + d] = v.w;
    }
    __syncthreads();
    int hr = t >> 2, seg = t & 3;
    int n = b * 1024 + hw0 + hr;
    int sg0 = (d0 >> 3) + seg * 2;   // global hi-seg of first 8 halfs
    half8 hi[2], lo[2];
    #pragma unroll
    for (int p = 0; p < 2; p++) {
        #pragma unroll
        for (int j = 0; j < 8; j++) {
            float v = lt[hr * 68 + seg * 16 + p * 8 + j];
            _Float16 h = (_Float16)v;
            hi[p][j] = h;
            lo[p][j] = (_Float16)(v - (float)h);
        }
    }
    *(half8*)(Zp + ((size_t)(sg0 + 0) * 32768 + n) * 8) = hi[0];
    *(half8*)(Zp + ((size_t)(sg0 + 1) * 32768 + n) * 8) = hi[1];
    *(half8*)(Zp + ((size_t)(32 + sg0) * 32768 + n) * 8) = lo[0];
    *(half8*)(Zp + ((size_t)(33 + sg0) * 32768 + n) * 8) = lo[1];
}

// fused fp16-split GEMM (3 terms: zh.eh + zl.eh + zh.el) + argmin epilogue.
// block tile 128x128, 4 waves 64x64, mfma 32x32x16 f16, K=64/iter, 12 iters.
__global__ __launch_bounds__(256) void k_mm(const _Float16* __restrict__ Zp,
                                            const _Float16* __restrict__ Ep,
                                            const float* __restrict__ enorm,
                                            unsigned long long* __restrict__ row_best) {
    __shared__ __align__(16) char smem[32768];
    _Float16* Za = (_Float16*)smem;            // [8 segs][128 rows][8 halfs] 16KB
    _Float16* Ea = (_Float16*)(smem + 16384);  // same, for codes
    unsigned long long* slot = (unsigned long long*)smem; // [128][32] after loop

    int t = threadIdx.x;
    int lane = t & 63, wv = t >> 6;
    int b = blockIdx.x;
    int rt = (b & 7) + ((b >> 6) << 3);   // same-Z blocks -> same XCD (assumes %8 round-robin)
    int ct = (b >> 3) & 7;
    int row0 = rt * 128, code0 = ct * 128;

    int wr = wv >> 1, wc = wv & 1;
    int m31 = lane & 31, ko = lane >> 5;

    f32x16 acc[2][2];
    #pragma unroll
    for (int i = 0; i < 2; i++)
        #pragma unroll
        for (int j = 0; j < 2; j++)
            #pragma unroll
            for (int r = 0; r < 16; r++) acc[i][j][r] = 0.0f;

    const char* zgl = (const char*)Zp + ((size_t)(2 * wv) * 32768 + row0 + lane) * 16;
    const char* egl = (const char*)Ep + ((size_t)(2 * wv) * 1024 + code0 + lane) * 16;
    _Float16* zld = Za + (2 * wv) * 1024;
    _Float16* eld = Ea + (2 * wv) * 1024;

    for (int c = 0; c < 12; c++) {
        int kz = (c < 8) ? c : (c - 8);
        int ge = (c < 4) ? c * 8 : (c < 8) ? (c - 4) * 8 : 32 + (c - 8) * 8;
        const char* zg = zgl + (size_t)kz * 8 * 32768 * 16;
        const char* eg = egl + (size_t)ge * 1024 * 16;
        gll16(zg, zld);
        gll16(zg + 64 * 16, zld + 512);
        gll16(zg + 32768 * 16, zld + 1024);
        gll16(zg + 32768 * 16 + 64 * 16, zld + 1536);
        gll16(eg, eld);
        gll16(eg + 64 * 16, eld + 512);
        gll16(eg + 1024 * 16, eld + 1024);
        gll16(eg + 1024 * 16 + 64 * 16, eld + 1536);
        __syncthreads();
        #pragma unroll
        for (int ks = 0; ks < 4; ks++) {
            int sseg = 2 * ks + ko;
            half8 a0 = *(const half8*)(Za + sseg * 1024 + (wr * 64 + m31) * 8);
            half8 a1 = *(const half8*)(Za + sseg * 1024 + (wr * 64 + 32 + m31) * 8);
            half8 b0 = *(const half8*)(Ea + sseg * 1024 + (wc * 64 + m31) * 8);
            half8 b1 = *(const half8*)(Ea + sseg * 1024 + (wc * 64 + 32 + m31) * 8);
            acc[0][0] = __builtin_amdgcn_mfma_f32_32x32x16_f16(a0, b0, acc[0][0], 0, 0, 0);
            acc[0][1] = __builtin_amdgcn_mfma_f32_32x32x16_f16(a0, b1, acc[0][1], 0, 0, 0);
            acc[1][0] = __builtin_amdgcn_mfma_f32_32x32x16_f16(a1, b0, acc[1][0], 0, 0, 0);
            acc[1][1] = __builtin_amdgcn_mfma_f32_32x32x16_f16(a1, b1, acc[1][1], 0, 0, 0);
        }
        __syncthreads();
    }

    float en0 = enorm[code0 + wc * 64 + m31];
    float en1 = enorm[code0 + wc * 64 + 32 + m31];
    unsigned int col0 = code0 + wc * 64 + m31;
    unsigned int col1 = col0 + 32;

    if (wc == 0) {
        #pragma unroll
        for (int mt = 0; mt < 2; mt++)
            #pragma unroll
            for (int j = 0; j < 16; j++) {
                int row = wr * 64 + mt * 32 + 4 * ko + (j & 3) + 8 * (j >> 2);
                unsigned long long p0 = ((unsigned long long)fenc(en0 - 2.0f * acc[mt][0][j]) << 32) | col0;
                unsigned long long p1 = ((unsigned long long)fenc(en1 - 2.0f * acc[mt][1][j]) << 32) | col1;
                slot[row * 32 + ((m31 + row) & 31)] = umin64(p0, p1);
            }
    }
    __syncthreads();
    if (wc == 1) {
        #pragma unroll
        for (int mt = 0; mt < 2; mt++)
            #pragma unroll
            for (int j = 0; j < 16; j++) {
                int row = wr * 64 + mt * 32 + 4 * ko + (j & 3) + 8 * (j >> 2);
                unsigned long long p0 = ((unsigned long long)fenc(en0 - 2.0f * acc[mt][0][j]) << 32) | col0;
                unsigned long long p1 = ((unsigned long long)fenc(en1 - 2.0f * acc[mt][1][j]) << 32) | col1;
                atomicMin(&slot[row * 32 + ((m31 + row) & 31)], umin64(p0, p1));
            }
    }
    __syncthreads();
    if (t < 128) {
        unsigned long long m = slot[t * 32 + (t & 31)];
        #pragma unroll
        for (int i = 1; i < 32; i++) m = umin64(m, slot[t * 32 + ((i + t) & 31)]);
        atomicMin(&row_best[row0 + t], m);
    }
}

__global__ __launch_bounds__(256) void k_fin_idx(const unsigned long long* __restrict__ rb,
                                                 int* __restrict__ idxs, float* __restrict__ out) {
    int i = blockIdx.x * 256 + threadIdx.x;
    if (i < N_ROWS) {
        int id = (int)(rb[i] & 0xFFFFFFFFull);
        idxs[i] = id;
        out[O_IDX + i] = (float)id;
    }
}

__global__ __launch_bounds__(256) void k_counts(const int* __restrict__ idxs,
                                                float* __restrict__ counts) {
    __shared__ float hist[K_CODES];
    int t = threadIdx.x;
    #pragma unroll
    for (int j = 0; j < 4; j++) hist[j * 256 + t] = 0.0f;
    __syncthreads();
    int n0 = blockIdx.x * 1024;
    #pragma unroll
    for (int i = 0; i < 4; i++) {
        int id = idxs[n0 + i * 256 + t];
        atomicAdd(&hist[id], 1.0f);
    }
    __syncthreads();
    #pragma unroll
    for (int j = 0; j < 4; j++) {
        float h = hist[j * 256 + t];
        if (h != 0.0f) atomicAdd(&counts[j * 256 + t], h);
    }
}

// dw partial segment-sum: block (s-chunk, d). float4/int4 loads, LDS acc[1024],
// flush as PLAIN coalesced stores to part[s][d][1024] (no global atomics).
__global__ __launch_bounds__(256) void k_dw(const float* __restrict__ z_e,
                                            const int* __restrict__ idxs,
                                            float* __restrict__ part) {
    __shared__ float acc[K_CODES];
    int t = threadIdx.x;
    int s = blockIdx.x;   // 0..7
    int d = blockIdx.y;   // 0..255
    #pragma unroll
    for (int j = 0; j < 4; j++) acc[j * 256 + t] = 0.0f;
    __syncthreads();
    #pragma unroll
    for (int i = 0; i < 4; i++) {
        int b = s * 4 + i;
        int4 id4 = *(const int4*)(idxs + b * 1024 + t * 4);
        float4 v = *(const float4*)(z_e + (size_t)b * 262144 + (size_t)d * 1024 + t * 4);
        atomicAdd(&acc[id4.x], v.x);
        atomicAdd(&acc[id4.y], v.y);
        atomicAdd(&acc[id4.z], v.z);
        atomicAdd(&acc[id4.w], v.w);
    }
    __syncthreads();
    float* pr = part + ((size_t)s * 256 + d) * 1024;
    #pragma unroll
    for (int j = 0; j < 4; j++) pr[j * 256 + t] = acc[j * 256 + t];
}

// reduce 8 partials + EMA finalize. block = 64-code x 64-d tile.
__global__ __launch_bounds__(256) void k_red(const float* __restrict__ part,
                                             const float* __restrict__ ema_cs,
                                             const float* __restrict__ ema_w,
                                             const float* __restrict__ counts,
                                             float* __restrict__ out) {
    __shared__ float tile[64 * 69];   // [d][k], pad 69
    __shared__ float csl[64];
    int t = threadIdx.x;
    int k0 = blockIdx.x * 64, d0 = blockIdx.y * 64;
    int dr = t >> 4, kc = t & 15;
    float4 sum[4] = {};
    for (int s = 0; s < 8; s++) {
        const float* pb = part + ((size_t)s * 256 + d0) * 1024 + k0 + kc * 4;
        #pragma unroll
        for (int q = 0; q < 4; q++) {
            float4 v = *(const float4*)(pb + (size_t)(dr + 16 * q) * 1024);
            sum[q].x += v.x; sum[q].y += v.y; sum[q].z += v.z; sum[q].w += v.w;
        }
    }
    if (t < 64) csl[t] = 0.99f * ema_cs[k0 + t] + 0.01f * counts[k0 + t];
    #pragma unroll
    for (int q = 0; q < 4; q++) {
        float* p = tile + (dr + 16 * q) * 69 + kc * 4;
        p[0] = sum[q].x; p[1] = sum[q].y; p[2] = sum[q].z; p[3] = sum[q].w;
    }
    __syncthreads();
    int kk = t >> 2, dq = t & 3;
    int k = k0 + kk;
    float inv = 1.0f / (csl[kk] + 1e-5f);
    #pragma unroll
    for (int j4 = 0; j4 < 4; j4++) {
        int dd = dq * 16 + j4 * 4;
        size_t kd = (size_t)k * 256 + d0 + dd;
        float4 w = *(const float4*)(ema_w + kd);
        float4 nw;
        nw.x = 0.99f * w.x + 0.01f * tile[(dd + 0) * 69 + kk];
        nw.y = 0.99f * w.y + 0.01f * tile[(dd + 1) * 69 + kk];
        nw.z = 0.99f * w.z + 0.01f * tile[(dd + 2) * 69 + kk];
        nw.w = 0.99f * w.w + 0.01f * tile[(dd + 3) * 69 + kk];
        *(float4*)(out + O_EMAW + kd) = nw;
        float4 ne = {nw.x * inv, nw.y * inv, nw.z * inv, nw.w * inv};
        *(float4*)(out + O_EMB + kd) = ne;
    }
    if (blockIdx.y == 0 && t < 64) out[O_CS + k0 + t] = csl[t];
    if (blockIdx.x == 0 && blockIdx.y == 0 && t == 0) out[O_LOSS] = 0.0f;
}

// tiled transpose-gather: block = 64 hw x 64 d.
__global__ __launch_bounds__(256) void k_gather(const float* __restrict__ z_e,
                                                const int* __restrict__ idxs,
                                                float* __restrict__ out) {
    __shared__ float lt[64 * 68];
    __shared__ int sid[64];
    __shared__ float red[4];
    int t = threadIdx.x;
    int hw0 = blockIdx.x * 64, d0 = blockIdx.y * 64, b = blockIdx.z;
    if (t < 64) sid[t] = idxs[b * 1024 + hw0 + t];
    const float* src = z_e + (size_t)b * 262144 + (size_t)d0 * 1024 + hw0;
    int dl = t >> 4, hl = (t & 15) * 4;
    #pragma unroll
    for (int i = 0; i < 4; i++) {
        int d = dl + i * 16;
        float4 v = *(const float4*)(src + (size_t)d * 1024 + hl);
        lt[(hl + 0) * 68 + d] = v.x;
        lt[(hl + 1) * 68 + d] = v.y;
        lt[(hl + 2) * 68 + d] = v.z;
        lt[(hl + 3) * 68 + d] = v.w;
    }
    __syncthreads();
    int r = t >> 2, c = t & 3;
    const float* nrow = out + O_EMB + (size_t)sid[r] * 256 + d0;
    float lacc = 0.0f;
    #pragma unroll
    for (int it = 0; it < 4; it++) {
        int dd = it * 16 + c * 4;
        float4 q = *(const float4*)(nrow + dd);
        float* p = lt + r * 68 + dd;
        float z0 = p[0], z1 = p[1], z2 = p[2], z3 = p[3];
        p[0] = z0 + (q.x - z0);
        p[1] = z1 + (q.y - z1);
        p[2] = z2 + (q.z - z2);
        p[3] = z3 + (q.w - z3);
        float dx = z0 - q.x, dy = z1 - q.y, dz = z2 - q.z, dw4 = z3 - q.w;
        lacc += dx * dx + dy * dy + dz * dz + dw4 * dw4;
    }
    __syncthreads();
    float* dst = out + O_ZQ + (size_t)b * 262144 + (size_t)d0 * 1024 + hw0;
    #pragma unroll
    for (int i = 0; i < 4; i++) {
        int d = dl + i * 16;
        float4 w;
        w.x = lt[(hl + 0) * 68 + d];
        w.y = lt[(hl + 1) * 68 + d];
        w.z = lt[(hl + 2) * 68 + d];
        w.w = lt[(hl + 3) * 68 + d];
        *(float4*)(dst + (size_t)d * 1024 + hl) = w;
    }
    #pragma unroll
    for (int off = 32; off >= 1; off >>= 1) lacc += __shfl_down(lacc, off, 64);
    int lane = t & 63, wv = t >> 6;
    if (lane == 0) red[wv] = lacc;
    __syncthreads();
    if (t == 0) {
        float s = (red[0] + red[1]) + (red[2] + red[3]);
        atomicAdd(out + O_LOSS, s * 2.9802322387695312e-08f); // * BETA / NELEM
    }
}

extern "C" void kernel_launch(void* const* d_in, const int* in_sizes, int n_in,
                              void* d_out, int out_size, void* d_ws, size_t ws_size,
                              hipStream_t stream) {
    const float* z_e = (const float*)d_in[0];
    const float* emb = (const float*)d_in[1];
    const float* ema_cs = (const float*)d_in[2];
    const float* ema_w = (const float*)d_in[3];
    float* out = (float*)d_out;
    float* ws = (float*)d_ws;

    float* counts = ws + WS_COUNTS;
    float* enorm = ws + WS_ENORM;
    unsigned long long* row_best = (unsigned long long*)((char*)d_ws + WS_ROWBEST_BYTES);
    int* idxs = (int*)((char*)d_ws + WS_IDX_BYTES);

    _Float16* Zp = (_Float16*)d_out;                        // dead after k_mm
    _Float16* Ep = (_Float16*)((char*)d_out + EP_BYTE_OFF); // dead after k_red
    float* part = (float*)d_out;                            // 8 MB, reuses Zp region after k_mm

    k_init<<<128, 256, 0, stream>>>(ws);
    k_conv_e<<<1024, 256, 0, stream>>>(emb, Ep, enorm);
    k_conv_z<<<dim3(16, 4, 32), 256, 0, stream>>>(z_e, Zp);
    k_mm<<<2048, 256, 0, stream>>>(Zp, Ep, enorm, row_best);
    k_fin_idx<<<128, 256, 0, stream>>>(row_best, idxs, out);
    k_counts<<<32, 256, 0, stream>>>(idxs, counts);
    k_dw<<<dim3(8, 256), 256, 0, stream>>>(z_e, idxs, part);
    k_red<<<dim3(16, 4), 256, 0, stream>>>(part, ema_cs, ema_w, counts, out);
    k_gather<<<dim3(16, 4, 32), 256, 0, stream>>>(z_e, idxs, out);
}